// Round 4
// baseline (310.542 us; speedup 1.0000x reference)
//
#include <hip/hip_runtime.h>

#define MEM_SIZE 16777216
#define N4 (MEM_SIZE / 4)
#define COPY_BLOCKS 4096

typedef float floatx4 __attribute__((ext_vector_type(4)));  // clang-native vec for nontemporal builtins

// ---- faithful soft-gate math (fp32, mirrors reference formulas exactly;
// ---- rounds 1-2 benched absmax 0.0 with these) ----

__device__ __forceinline__ float silu_f(float x) {
    return x / (1.0f + __expf(-x));
}

// silu_threshold(x, s=20) = (silu(20x+10) - silu(20x-10)) / 20
__device__ __forceinline__ float silu_th(float x) {
    float d = 20.0f * x;
    return (silu_f(d + 10.0f) - silu_f(d - 10.0f)) * 0.05f;
}

__device__ __forceinline__ float eq_g(float a, float b) {
    float diff = a - b;
    return silu_th(diff + 0.5f) * silu_th(0.5f - diff);
}
__device__ __forceinline__ float ge_g(float a, float b) { return silu_th(a - b + 0.5f); }
__device__ __forceinline__ float gt_g(float a, float b) { return silu_th(a - b - 0.5f); }

__device__ __forceinline__ float swiglu_mul_f(float a, float b) {
    return a * silu_f(b) - a * silu_f(-b);
}

__device__ __forceinline__ float pulse_f(float x, float c) {
    float d = x - c;
    return swiglu_mul_f(silu_th(d + 0.5f), silu_th(0.5f - d));
}

// Windowed soft-attention read: eq_gate support is |addr-pos| < ~2.5;
// beyond +/-5 contributions vanish below fp32 rounding.
__device__ float read_mem_soft(const float* mem, float addr) {
    float ca = rintf(addr);
    if (!(ca > -16.0f && ca < (float)MEM_SIZE + 16.0f)) return 0.0f;
    int c = (int)ca;
    float wsum = 0.0f, vsum = 0.0f;
    for (int d = -5; d <= 5; ++d) {
        int i = c + d;
        if (i < 0 || i >= MEM_SIZE) continue;
        float w = eq_g(addr, (float)i);
        wsum += w;
        vsum += w * mem[i];
    }
    return vsum / (wsum + 1e-8f);
}

// Single fused kernel:
//   block 0            : scalar VM step (overlaps the copy), publishes 5 write
//                        descriptors to ws[16..25], writes out[0..3]
//   blocks 1..COPY     : stream mem -> out+4 (non-temporal float4)
//   all blocks         : ACQ_REL atomic increment of ws counter; the LAST
//                        block applies the <=65-slot window patch (base values
//                        re-read from pristine `mem`, so only write-after-write
//                        ordering is needed — the counter provides it).
__global__ __launch_bounds__(256) void k_fused(
    const float* __restrict__ pc_p, const float* __restrict__ sp_p,
    const float* __restrict__ bp_p, const float* __restrict__ ax_p,
    const float* __restrict__ mem, float* __restrict__ out,
    float* __restrict__ ws)
{
    unsigned int* counter = (unsigned int*)ws;     // zeroed by memset node
    float* wsd = ws + 16;                          // descriptors, separate line

    __shared__ float s_ws[10];
    __shared__ unsigned int s_last;
    int t = threadIdx.x;

    if (blockIdx.x != 0) {
        // ---------------- copy path ----------------
        const floatx4* __restrict__ src = (const floatx4*)mem;
        floatx4* __restrict__ dst = (floatx4*)(out + 4);   // 16B-aligned
        int stride = COPY_BLOCKS * 256;
        for (int i = ((int)blockIdx.x - 1) * 256 + t; i < N4; i += stride) {
            floatx4 v = __builtin_nontemporal_load(&src[i]);
            __builtin_nontemporal_store(v, &dst[i]);
        }
    } else {
        // ---------------- step path (block 0) ----------------
        __shared__ float s_reads[5];
        __shared__ float sred[256];
        __shared__ float sres[3];

        float pc = pc_p[0], sp = sp_p[0], bp = bp_p[0], ax = ax_p[0];

        if (t < 5) {
            float addr = (t == 0) ? pc
                       : (t == 1) ? sp
                       : (t == 2) ? ax
                       : (t == 3) ? bp
                                  : (sp + 8.0f);
            s_reads[t] = read_mem_soft(mem, addr);
        }
        __syncthreads();

        float instruction   = s_reads[0];
        float stack_top     = s_reads[1];
        float li_result     = s_reads[2];
        float bp_from_stack = s_reads[3];
        float pc_from_stack = s_reads[4];

        float ax_safe = ax + eq_g(ax, 0.0f);

        // swiglu_div: 256 quotient terms, one per thread
        {
            float q  = (float)t;
            float t1 = stack_top - q * ax_safe + 0.5f;
            float t2 = stack_top - (q + 1.0f) * ax_safe + 0.5f;
            sred[t] = (silu_th(t1) - silu_th(t2)) * q;
        }
        __syncthreads();
        for (int off = 128; off >= 1; off >>= 1) {
            if (t < off) sred[t] += sred[t + off];
            __syncthreads();
        }
        if (t == 0) sres[0] = sred[0];
        __syncthreads();

        // shifts: 32 terms
        float shlterm = 0.0f, shrterm = 0.0f;
        if (t < 32) {
            float p  = ldexpf(1.0f, t);          // 2^i exact
            float pl = pulse_f(ax, (float)t);
            shlterm = swiglu_mul_f(stack_top, p) * pl;
            shrterm = floorf(stack_top / p) * pl;
        }
        sred[t] = shlterm;
        __syncthreads();
        for (int off = 128; off >= 1; off >>= 1) {
            if (t < off) sred[t] += sred[t + off];
            __syncthreads();
        }
        if (t == 0) sres[1] = sred[0];
        __syncthreads();
        sred[t] = shrterm;
        __syncthreads();
        for (int off = 128; off >= 1; off >>= 1) {
            if (t < off) sred[t] += sred[t + off];
            __syncthreads();
        }
        if (t == 0) sres[2] = sred[0];
        __syncthreads();

        if (t == 0) {
            float pc_next = pc + 8.0f;
            float imm     = floorf(instruction * (1.0f / 256.0f));
            float opcode  = instruction - imm * 256.0f;   // jnp.remainder(x,256)

            float add_result = stack_top + ax;
            float sub_result = stack_top - ax;
            float mul_result = swiglu_mul_f(stack_top, ax);
            float div_result = sres[0];
            float mod_result = stack_top - swiglu_mul_f(div_result, ax_safe);
            float shl_result = sres[1];
            float shr_result = sres[2];
            float or_result  = stack_top + ax - swiglu_mul_f(stack_top, ax);
            float xor_result = stack_top + ax - 2.0f * swiglu_mul_f(stack_top, ax);
            float and_result = swiglu_mul_f(stack_top, ax);
            float eq_result  = eq_g(stack_top, ax);
            float ne_result  = 1.0f - eq_g(stack_top, ax);
            float lt_result  = gt_g(ax, stack_top);
            float gt_result  = gt_g(stack_top, ax);
            float le_result  = ge_g(ax, stack_top);
            float ge_result  = ge_g(stack_top, ax);
            float lc_result  = li_result;
            float lea_result = bp + imm;

            float g_lea = eq_g(opcode, 0.0f),  g_imm = eq_g(opcode, 1.0f);
            float g_jmp = eq_g(opcode, 2.0f),  g_jsr = eq_g(opcode, 3.0f);
            float g_bz  = eq_g(opcode, 4.0f),  g_bnz = eq_g(opcode, 5.0f);
            float g_ent = eq_g(opcode, 6.0f),  g_adj = eq_g(opcode, 7.0f);
            float g_lev = eq_g(opcode, 8.0f),  g_li  = eq_g(opcode, 9.0f);
            float g_lc  = eq_g(opcode, 10.0f), g_si  = eq_g(opcode, 11.0f);
            float g_sc  = eq_g(opcode, 12.0f), g_psh = eq_g(opcode, 13.0f);
            float g_or  = eq_g(opcode, 14.0f), g_xor = eq_g(opcode, 15.0f);
            float g_and = eq_g(opcode, 16.0f), g_eq  = eq_g(opcode, 17.0f);
            float g_ne  = eq_g(opcode, 18.0f), g_lt  = eq_g(opcode, 19.0f);
            float g_gt  = eq_g(opcode, 20.0f), g_le  = eq_g(opcode, 21.0f);
            float g_ge  = eq_g(opcode, 22.0f), g_shl = eq_g(opcode, 23.0f);
            float g_shr = eq_g(opcode, 24.0f), g_add = eq_g(opcode, 25.0f);
            float g_sub = eq_g(opcode, 26.0f), g_mul = eq_g(opcode, 27.0f);
            float g_div = eq_g(opcode, 28.0f), g_mod = eq_g(opcode, 29.0f);

            float gate_sum = g_lea + g_imm + g_li + g_lc + g_add + g_sub + g_mul + g_div
                           + g_mod + g_shl + g_shr + g_or + g_xor + g_and + g_eq + g_ne
                           + g_lt + g_gt + g_le + g_ge;
            float new_ax = ax * (1.0f - gate_sum)
                + lea_result * g_lea + imm * g_imm + li_result * g_li + lc_result * g_lc
                + add_result * g_add + sub_result * g_sub + mul_result * g_mul
                + div_result * g_div + mod_result * g_mod + shl_result * g_shl
                + shr_result * g_shr + or_result * g_or + xor_result * g_xor
                + and_result * g_and + eq_result * g_eq + ne_result * g_ne
                + lt_result * g_lt + gt_result * g_gt + le_result * g_le + ge_result * g_ge;

            float pops = g_add + g_sub + g_mul + g_div + g_mod + g_shl + g_shr + g_or + g_xor
                       + g_and + g_eq + g_ne + g_lt + g_gt + g_le + g_ge;
            float new_sp = sp * (1.0f - g_psh - g_adj - g_ent - g_lev - pops)
                + (sp - 8.0f) * g_psh + (sp + imm) * g_adj + (sp - imm) * g_ent
                + bp * g_lev + (sp + 8.0f) * pops;

            float new_bp = bp * (1.0f - g_ent - g_lev) + sp * g_ent + bp_from_stack * g_lev;

            float eq_ax0   = eq_g(ax, 0.0f);
            float bz_take  = swiglu_mul_f(g_bz, eq_ax0);
            float bnz_take = swiglu_mul_f(g_bnz, 1.0f - eq_ax0);
            float new_pc = pc_next * (1.0f - g_jmp - g_jsr - bz_take - bnz_take - g_lev)
                + imm * g_jmp + imm * g_jsr + imm * bz_take + imm * bnz_take
                + pc_from_stack * g_lev;

            out[0] = rintf(new_pc);
            out[1] = rintf(new_sp);
            out[2] = rintf(new_bp);
            out[3] = rintf(new_ax);

            // descriptors (addr, value), reference order: psh, jsr, ent, si, sc
            wsd[0] = (sp - 8.0f) * g_psh;  wsd[1] = ax * g_psh;
            wsd[2] = (sp - 8.0f) * g_jsr;  wsd[3] = pc_next * g_jsr;
            wsd[4] = (sp - 8.0f) * g_ent;  wsd[5] = bp * g_ent;
            wsd[6] = stack_top * g_si;     wsd[7] = ax * g_si;
            wsd[8] = stack_top * g_sc;     wsd[9] = ax * g_sc;
        }
    }

    // ---------------- completion rendezvous ----------------
    __syncthreads();
    if (t == 0) {
        unsigned int old = __hip_atomic_fetch_add(counter, 1u,
                                                  __ATOMIC_ACQ_REL,
                                                  __HIP_MEMORY_SCOPE_AGENT);
        s_last = (old == (unsigned int)gridDim.x - 1u) ? 1u : 0u;
    }
    __syncthreads();

    if (s_last) {
        // last-finishing block applies the 5 soft writes
        if (t < 10) s_ws[t] = wsd[t];
        __syncthreads();

        const int R = 6, W = 2 * R + 1;        // 13-slot window per write
        if (t >= 5 * W) return;
        int j = t / W;
        int d = t % W - R;

        float cj = rintf(s_ws[2 * j]);
        if (!(cj > -64.0f && cj < (float)MEM_SIZE + 64.0f)) return;
        int slot = (int)cj + d;
        if (slot < 0 || slot >= MEM_SIZE) return;

        for (int j2 = 0; j2 < j; ++j2) {
            float c2 = rintf(s_ws[2 * j2]);
            if (c2 > -64.0f && c2 < (float)MEM_SIZE + 64.0f) {
                int cc = (int)c2;
                if (slot >= cc - R && slot <= cc + R) return;  // earlier index owns it
            }
        }

        float fs = (float)slot;
        float m = mem[slot];                 // pristine input value
        #pragma unroll
        for (int jj = 0; jj < 5; ++jj) {
            float a = s_ws[2 * jj], v = s_ws[2 * jj + 1];
            float g = eq_g(a, fs);
            m = m * (1.0f - g) + v * g;
        }
        out[4 + slot] = m;
    }
}

extern "C" void kernel_launch(void* const* d_in, const int* in_sizes, int n_in,
                              void* d_out, int out_size, void* d_ws, size_t ws_size,
                              hipStream_t stream) {
    const float* pc  = (const float*)d_in[0];
    const float* sp  = (const float*)d_in[1];
    const float* bp  = (const float*)d_in[2];
    const float* ax  = (const float*)d_in[3];
    const float* mem = (const float*)d_in[4];
    float* out = (float*)d_out;
    float* ws  = (float*)d_ws;

    (void)hipMemsetAsync(ws, 0, sizeof(unsigned int), stream);   // zero the counter
    hipLaunchKernelGGL(k_fused, dim3(COPY_BLOCKS + 1), dim3(256), 0, stream,
                       pc, sp, bp, ax, mem, out, ws);
}

// Round 5
// 299.000 us; speedup vs baseline: 1.0386x; 1.0386x over previous
//
#include <hip/hip_runtime.h>

#define MEM_SIZE 16777216
#define N4 (MEM_SIZE / 4)
#define COPY_BLOCKS 4096

// ---- faithful soft-gate math (fp32, mirrors reference formulas exactly;
// ---- rounds 1-2-4 benched absmax 0.0 with these) ----

__device__ __forceinline__ float silu_f(float x) {
    return x / (1.0f + __expf(-x));
}

// silu_threshold(x, s=20) = (silu(20x+10) - silu(20x-10)) / 20
__device__ __forceinline__ float silu_th(float x) {
    float d = 20.0f * x;
    return (silu_f(d + 10.0f) - silu_f(d - 10.0f)) * 0.05f;
}

__device__ __forceinline__ float eq_g(float a, float b) {
    float diff = a - b;
    return silu_th(diff + 0.5f) * silu_th(0.5f - diff);
}
__device__ __forceinline__ float ge_g(float a, float b) { return silu_th(a - b + 0.5f); }
__device__ __forceinline__ float gt_g(float a, float b) { return silu_th(a - b - 0.5f); }

__device__ __forceinline__ float swiglu_mul_f(float a, float b) {
    return a * silu_f(b) - a * silu_f(-b);
}

__device__ __forceinline__ float pulse_f(float x, float c) {
    float d = x - c;
    return swiglu_mul_f(silu_th(d + 0.5f), silu_th(0.5f - d));
}

// Windowed soft-attention read: eq_gate support is |addr-pos| < ~2.5;
// beyond +/-5 contributions vanish below fp32 rounding.
__device__ float read_mem_soft(const float* mem, float addr) {
    float ca = rintf(addr);
    if (!(ca > -16.0f && ca < (float)MEM_SIZE + 16.0f)) return 0.0f;
    int c = (int)ca;
    float wsum = 0.0f, vsum = 0.0f;
    for (int d = -5; d <= 5; ++d) {
        int i = c + d;
        if (i < 0 || i >= MEM_SIZE) continue;
        float w = eq_g(addr, (float)i);
        wsum += w;
        vsum += w * mem[i];
    }
    return vsum / (wsum + 1e-8f);
}

// Single fused kernel:
//   block 0            : scalar VM step (overlaps the copy), publishes 5 write
//                        descriptors to ws[16..25], writes out[0..3]
//   blocks 1..COPY     : stream mem -> out+4 (PLAIN float4 — nontemporal was a
//                        10x regression on gfx950, round 4)
//   all blocks         : ACQ_REL atomic increment of ws counter; the LAST
//                        block applies the <=65-slot window patch (base values
//                        re-read from pristine `mem`, so only write-after-write
//                        ordering is needed — the counter provides it).
__global__ __launch_bounds__(256) void k_fused(
    const float* __restrict__ pc_p, const float* __restrict__ sp_p,
    const float* __restrict__ bp_p, const float* __restrict__ ax_p,
    const float* __restrict__ mem, float* __restrict__ out,
    float* __restrict__ ws)
{
    unsigned int* counter = (unsigned int*)ws;     // zeroed by memset node
    float* wsd = ws + 16;                          // descriptors, separate line

    __shared__ float s_ws[10];
    __shared__ unsigned int s_last;
    int t = threadIdx.x;

    if (blockIdx.x != 0) {
        // ---------------- copy path ----------------
        const float4* __restrict__ src = (const float4*)mem;
        float4* __restrict__ dst = (float4*)(out + 4);   // 16B-aligned
        int stride = COPY_BLOCKS * 256;
        for (int i = ((int)blockIdx.x - 1) * 256 + t; i < N4; i += stride)
            dst[i] = src[i];
    } else {
        // ---------------- step path (block 0) ----------------
        __shared__ float s_reads[5];
        __shared__ float sred[256];
        __shared__ float sres[3];

        float pc = pc_p[0], sp = sp_p[0], bp = bp_p[0], ax = ax_p[0];

        if (t < 5) {
            float addr = (t == 0) ? pc
                       : (t == 1) ? sp
                       : (t == 2) ? ax
                       : (t == 3) ? bp
                                  : (sp + 8.0f);
            s_reads[t] = read_mem_soft(mem, addr);
        }
        __syncthreads();

        float instruction   = s_reads[0];
        float stack_top     = s_reads[1];
        float li_result     = s_reads[2];
        float bp_from_stack = s_reads[3];
        float pc_from_stack = s_reads[4];

        float ax_safe = ax + eq_g(ax, 0.0f);

        // swiglu_div: 256 quotient terms, one per thread
        {
            float q  = (float)t;
            float t1 = stack_top - q * ax_safe + 0.5f;
            float t2 = stack_top - (q + 1.0f) * ax_safe + 0.5f;
            sred[t] = (silu_th(t1) - silu_th(t2)) * q;
        }
        __syncthreads();
        for (int off = 128; off >= 1; off >>= 1) {
            if (t < off) sred[t] += sred[t + off];
            __syncthreads();
        }
        if (t == 0) sres[0] = sred[0];
        __syncthreads();

        // shifts: 32 terms
        float shlterm = 0.0f, shrterm = 0.0f;
        if (t < 32) {
            float p  = ldexpf(1.0f, t);          // 2^i exact
            float pl = pulse_f(ax, (float)t);
            shlterm = swiglu_mul_f(stack_top, p) * pl;
            shrterm = floorf(stack_top / p) * pl;
        }
        sred[t] = shlterm;
        __syncthreads();
        for (int off = 128; off >= 1; off >>= 1) {
            if (t < off) sred[t] += sred[t + off];
            __syncthreads();
        }
        if (t == 0) sres[1] = sred[0];
        __syncthreads();
        sred[t] = shrterm;
        __syncthreads();
        for (int off = 128; off >= 1; off >>= 1) {
            if (t < off) sred[t] += sred[t + off];
            __syncthreads();
        }
        if (t == 0) sres[2] = sred[0];
        __syncthreads();

        if (t == 0) {
            float pc_next = pc + 8.0f;
            float imm     = floorf(instruction * (1.0f / 256.0f));
            float opcode  = instruction - imm * 256.0f;   // jnp.remainder(x,256)

            float add_result = stack_top + ax;
            float sub_result = stack_top - ax;
            float mul_result = swiglu_mul_f(stack_top, ax);
            float div_result = sres[0];
            float mod_result = stack_top - swiglu_mul_f(div_result, ax_safe);
            float shl_result = sres[1];
            float shr_result = sres[2];
            float or_result  = stack_top + ax - swiglu_mul_f(stack_top, ax);
            float xor_result = stack_top + ax - 2.0f * swiglu_mul_f(stack_top, ax);
            float and_result = swiglu_mul_f(stack_top, ax);
            float eq_result  = eq_g(stack_top, ax);
            float ne_result  = 1.0f - eq_g(stack_top, ax);
            float lt_result  = gt_g(ax, stack_top);
            float gt_result  = gt_g(stack_top, ax);
            float le_result  = ge_g(ax, stack_top);
            float ge_result  = ge_g(stack_top, ax);
            float lc_result  = li_result;
            float lea_result = bp + imm;

            float g_lea = eq_g(opcode, 0.0f),  g_imm = eq_g(opcode, 1.0f);
            float g_jmp = eq_g(opcode, 2.0f),  g_jsr = eq_g(opcode, 3.0f);
            float g_bz  = eq_g(opcode, 4.0f),  g_bnz = eq_g(opcode, 5.0f);
            float g_ent = eq_g(opcode, 6.0f),  g_adj = eq_g(opcode, 7.0f);
            float g_lev = eq_g(opcode, 8.0f),  g_li  = eq_g(opcode, 9.0f);
            float g_lc  = eq_g(opcode, 10.0f), g_si  = eq_g(opcode, 11.0f);
            float g_sc  = eq_g(opcode, 12.0f), g_psh = eq_g(opcode, 13.0f);
            float g_or  = eq_g(opcode, 14.0f), g_xor = eq_g(opcode, 15.0f);
            float g_and = eq_g(opcode, 16.0f), g_eq  = eq_g(opcode, 17.0f);
            float g_ne  = eq_g(opcode, 18.0f), g_lt  = eq_g(opcode, 19.0f);
            float g_gt  = eq_g(opcode, 20.0f), g_le  = eq_g(opcode, 21.0f);
            float g_ge  = eq_g(opcode, 22.0f), g_shl = eq_g(opcode, 23.0f);
            float g_shr = eq_g(opcode, 24.0f), g_add = eq_g(opcode, 25.0f);
            float g_sub = eq_g(opcode, 26.0f), g_mul = eq_g(opcode, 27.0f);
            float g_div = eq_g(opcode, 28.0f), g_mod = eq_g(opcode, 29.0f);

            float gate_sum = g_lea + g_imm + g_li + g_lc + g_add + g_sub + g_mul + g_div
                           + g_mod + g_shl + g_shr + g_or + g_xor + g_and + g_eq + g_ne
                           + g_lt + g_gt + g_le + g_ge;
            float new_ax = ax * (1.0f - gate_sum)
                + lea_result * g_lea + imm * g_imm + li_result * g_li + lc_result * g_lc
                + add_result * g_add + sub_result * g_sub + mul_result * g_mul
                + div_result * g_div + mod_result * g_mod + shl_result * g_shl
                + shr_result * g_shr + or_result * g_or + xor_result * g_xor
                + and_result * g_and + eq_result * g_eq + ne_result * g_ne
                + lt_result * g_lt + gt_result * g_gt + le_result * g_le + ge_result * g_ge;

            float pops = g_add + g_sub + g_mul + g_div + g_mod + g_shl + g_shr + g_or + g_xor
                       + g_and + g_eq + g_ne + g_lt + g_gt + g_le + g_ge;
            float new_sp = sp * (1.0f - g_psh - g_adj - g_ent - g_lev - pops)
                + (sp - 8.0f) * g_psh + (sp + imm) * g_adj + (sp - imm) * g_ent
                + bp * g_lev + (sp + 8.0f) * pops;

            float new_bp = bp * (1.0f - g_ent - g_lev) + sp * g_ent + bp_from_stack * g_lev;

            float eq_ax0   = eq_g(ax, 0.0f);
            float bz_take  = swiglu_mul_f(g_bz, eq_ax0);
            float bnz_take = swiglu_mul_f(g_bnz, 1.0f - eq_ax0);
            float new_pc = pc_next * (1.0f - g_jmp - g_jsr - bz_take - bnz_take - g_lev)
                + imm * g_jmp + imm * g_jsr + imm * bz_take + imm * bnz_take
                + pc_from_stack * g_lev;

            out[0] = rintf(new_pc);
            out[1] = rintf(new_sp);
            out[2] = rintf(new_bp);
            out[3] = rintf(new_ax);

            // descriptors (addr, value), reference order: psh, jsr, ent, si, sc
            wsd[0] = (sp - 8.0f) * g_psh;  wsd[1] = ax * g_psh;
            wsd[2] = (sp - 8.0f) * g_jsr;  wsd[3] = pc_next * g_jsr;
            wsd[4] = (sp - 8.0f) * g_ent;  wsd[5] = bp * g_ent;
            wsd[6] = stack_top * g_si;     wsd[7] = ax * g_si;
            wsd[8] = stack_top * g_sc;     wsd[9] = ax * g_sc;
        }
    }

    // ---------------- completion rendezvous ----------------
    __syncthreads();
    if (t == 0) {
        unsigned int old = __hip_atomic_fetch_add(counter, 1u,
                                                  __ATOMIC_ACQ_REL,
                                                  __HIP_MEMORY_SCOPE_AGENT);
        s_last = (old == (unsigned int)gridDim.x - 1u) ? 1u : 0u;
    }
    __syncthreads();

    if (s_last) {
        // last-finishing block applies the 5 soft writes
        if (t < 10) s_ws[t] = wsd[t];
        __syncthreads();

        const int R = 6, W = 2 * R + 1;        // 13-slot window per write
        if (t >= 5 * W) return;
        int j = t / W;
        int d = t % W - R;

        float cj = rintf(s_ws[2 * j]);
        if (!(cj > -64.0f && cj < (float)MEM_SIZE + 64.0f)) return;
        int slot = (int)cj + d;
        if (slot < 0 || slot >= MEM_SIZE) return;

        for (int j2 = 0; j2 < j; ++j2) {
            float c2 = rintf(s_ws[2 * j2]);
            if (c2 > -64.0f && c2 < (float)MEM_SIZE + 64.0f) {
                int cc = (int)c2;
                if (slot >= cc - R && slot <= cc + R) return;  // earlier index owns it
            }
        }

        float fs = (float)slot;
        float m = mem[slot];                 // pristine input value
        #pragma unroll
        for (int jj = 0; jj < 5; ++jj) {
            float a = s_ws[2 * jj], v = s_ws[2 * jj + 1];
            float g = eq_g(a, fs);
            m = m * (1.0f - g) + v * g;
        }
        out[4 + slot] = m;
    }
}

extern "C" void kernel_launch(void* const* d_in, const int* in_sizes, int n_in,
                              void* d_out, int out_size, void* d_ws, size_t ws_size,
                              hipStream_t stream) {
    const float* pc  = (const float*)d_in[0];
    const float* sp  = (const float*)d_in[1];
    const float* bp  = (const float*)d_in[2];
    const float* ax  = (const float*)d_in[3];
    const float* mem = (const float*)d_in[4];
    float* out = (float*)d_out;
    float* ws  = (float*)d_ws;

    (void)hipMemsetAsync(ws, 0, sizeof(unsigned int), stream);   // zero the counter
    hipLaunchKernelGGL(k_fused, dim3(COPY_BLOCKS + 1), dim3(256), 0, stream,
                       pc, sp, bp, ax, mem, out, ws);
}

// Round 6
// 122.096 us; speedup vs baseline: 2.5434x; 2.4489x over previous
//
#include <hip/hip_runtime.h>

#define MEM_SIZE 16777216
#define N4 (MEM_SIZE / 4)
#define COPY_BLOCKS 4096

// ---- faithful soft-gate math (fp32, mirrors reference formulas exactly;
// ---- rounds 1/2/4/5 all benched absmax 0.0 with these) ----

__device__ __forceinline__ float silu_f(float x) {
    return x / (1.0f + __expf(-x));
}

// silu_threshold(x, s=20) = (silu(20x+10) - silu(20x-10)) / 20
__device__ __forceinline__ float silu_th(float x) {
    float d = 20.0f * x;
    return (silu_f(d + 10.0f) - silu_f(d - 10.0f)) * 0.05f;
}

__device__ __forceinline__ float eq_g(float a, float b) {
    float diff = a - b;
    return silu_th(diff + 0.5f) * silu_th(0.5f - diff);
}
__device__ __forceinline__ float ge_g(float a, float b) { return silu_th(a - b + 0.5f); }
__device__ __forceinline__ float gt_g(float a, float b) { return silu_th(a - b - 0.5f); }

__device__ __forceinline__ float swiglu_mul_f(float a, float b) {
    return a * silu_f(b) - a * silu_f(-b);
}

__device__ __forceinline__ float pulse_f(float x, float c) {
    float d = x - c;
    return swiglu_mul_f(silu_th(d + 0.5f), silu_th(0.5f - d));
}

// Windowed soft-attention read: eq_gate support is |addr-pos| < ~2.5;
// beyond +/-5 contributions vanish below fp32 rounding.
__device__ float read_mem_soft(const float* mem, float addr) {
    float ca = rintf(addr);
    if (!(ca > -16.0f && ca < (float)MEM_SIZE + 16.0f)) return 0.0f;
    int c = (int)ca;
    float wsum = 0.0f, vsum = 0.0f;
    for (int d = -5; d <= 5; ++d) {
        int i = c + d;
        if (i < 0 || i >= MEM_SIZE) continue;
        float w = eq_g(addr, (float)i);
        wsum += w;
        vsum += w * mem[i];
    }
    return vsum / (wsum + 1e-8f);
}

// float4-aligned window [c-7, c+7] -> inclusive float4 index range [lo4, hi4].
// Empty window encoded as lo4=1, hi4=0. MUST be identical for copy blocks and
// block 0 (it defines the ownership partition of out[]).
__device__ __forceinline__ void win4(int c, bool valid, int& lo4, int& hi4) {
    if (!valid) { lo4 = 1; hi4 = 0; return; }
    int a = c - 7, b = c + 7;
    lo4 = (a >= 0) ? (a >> 2) : -(((-a) + 3) >> 2);   // floor_div(a,4)
    hi4 = (b >= 0) ? (b >> 2) : -(((-b) + 3) >> 2);
    if (lo4 < 0) lo4 = 0;
    if (hi4 > N4 - 1) hi4 = N4 - 1;
    if (lo4 > hi4) { lo4 = 1; hi4 = 0; }
}

// The 3 possible patch-window centers, computable from inputs alone:
//   w0: 0                      (gated-off writes collapse to addr ~0)
//   w1: rint(sp-8)             (psh / jsr / ent)
//   w2: rint(mem[rint(sp)])    (si / sc target = stack_top; hard read rounds
//                               identically to the soft read: integer base +-1e-6)
__device__ void calc_windows(const float* sp_p, const float* mem,
                             int lo[3], int hi[3]) {
    float sp = sp_p[0];
    win4(0, true, lo[0], hi[0]);
    float c1f = rintf(sp - 8.0f);
    bool v1 = (c1f > -32.0f && c1f < (float)MEM_SIZE + 32.0f);
    win4(v1 ? (int)c1f : 0, v1, lo[1], hi[1]);
    float spr = rintf(sp);
    bool spv = (spr >= 0.0f && spr < (float)MEM_SIZE);
    float stf = spv ? rintf(mem[(int)spr]) : 0.0f;
    bool v2 = spv && (stf > -32.0f && stf < (float)MEM_SIZE + 32.0f);
    win4(v2 ? (int)stf : 0, v2, lo[2], hi[2]);
}

// Single fused kernel, NO cross-block synchronization:
//   blocks 1..4096 : copy mem -> out+4, skipping the 3 patch windows
//   block 0        : scalar VM step (overlaps copy), then writes the 3 patch
//                    windows itself with the 5 reference-order soft lerps.
// Every out[] address is written by exactly one thread -> no atomics/fences.
// (Round 4/5 lesson: agent-scope ACQ_REL rendezvous during streaming writes
// collapses BW ~10x on gfx950 via per-block L2 writeback/invalidate.)
__global__ __launch_bounds__(256) void k_fused(
    const float* __restrict__ pc_p, const float* __restrict__ sp_p,
    const float* __restrict__ bp_p, const float* __restrict__ ax_p,
    const float* __restrict__ mem, float* __restrict__ out)
{
    int t = threadIdx.x;

    if (blockIdx.x != 0) {
        // ---------------- copy path ----------------
        int lo[3], hi[3];
        calc_windows(sp_p, mem, lo, hi);
        const float4* __restrict__ src = (const float4*)mem;
        float4* __restrict__ dst = (float4*)(out + 4);   // 16B-aligned
        int stride = COPY_BLOCKS * 256;
        for (int i = ((int)blockIdx.x - 1) * 256 + t; i < N4; i += stride) {
            bool skip = (i >= lo[0] && i <= hi[0]) ||
                        (i >= lo[1] && i <= hi[1]) ||
                        (i >= lo[2] && i <= hi[2]);
            if (!skip) dst[i] = src[i];
        }
        return;
    }

    // ---------------- step path (block 0) ----------------
    __shared__ float s_reads[5];
    __shared__ float sred[256];
    __shared__ float sres[3];
    __shared__ float s_ws[10];   // 5 x (addr, value) descriptors

    float pc = pc_p[0], sp = sp_p[0], bp = bp_p[0], ax = ax_p[0];

    if (t < 5) {
        float addr = (t == 0) ? pc
                   : (t == 1) ? sp
                   : (t == 2) ? ax
                   : (t == 3) ? bp
                              : (sp + 8.0f);
        s_reads[t] = read_mem_soft(mem, addr);
    }
    __syncthreads();

    float instruction   = s_reads[0];
    float stack_top     = s_reads[1];
    float li_result     = s_reads[2];
    float bp_from_stack = s_reads[3];
    float pc_from_stack = s_reads[4];

    float ax_safe = ax + eq_g(ax, 0.0f);

    // swiglu_div: 256 quotient terms, one per thread
    {
        float q  = (float)t;
        float t1 = stack_top - q * ax_safe + 0.5f;
        float t2 = stack_top - (q + 1.0f) * ax_safe + 0.5f;
        sred[t] = (silu_th(t1) - silu_th(t2)) * q;
    }
    __syncthreads();
    for (int off = 128; off >= 1; off >>= 1) {
        if (t < off) sred[t] += sred[t + off];
        __syncthreads();
    }
    if (t == 0) sres[0] = sred[0];
    __syncthreads();

    // shifts: 32 terms
    float shlterm = 0.0f, shrterm = 0.0f;
    if (t < 32) {
        float p  = ldexpf(1.0f, t);          // 2^i exact
        float pl = pulse_f(ax, (float)t);
        shlterm = swiglu_mul_f(stack_top, p) * pl;
        shrterm = floorf(stack_top / p) * pl;
    }
    sred[t] = shlterm;
    __syncthreads();
    for (int off = 128; off >= 1; off >>= 1) {
        if (t < off) sred[t] += sred[t + off];
        __syncthreads();
    }
    if (t == 0) sres[1] = sred[0];
    __syncthreads();
    sred[t] = shrterm;
    __syncthreads();
    for (int off = 128; off >= 1; off >>= 1) {
        if (t < off) sred[t] += sred[t + off];
        __syncthreads();
    }
    if (t == 0) sres[2] = sred[0];
    __syncthreads();

    if (t == 0) {
        float pc_next = pc + 8.0f;
        float imm     = floorf(instruction * (1.0f / 256.0f));
        float opcode  = instruction - imm * 256.0f;   // jnp.remainder(x,256)

        float add_result = stack_top + ax;
        float sub_result = stack_top - ax;
        float mul_result = swiglu_mul_f(stack_top, ax);
        float div_result = sres[0];
        float mod_result = stack_top - swiglu_mul_f(div_result, ax_safe);
        float shl_result = sres[1];
        float shr_result = sres[2];
        float or_result  = stack_top + ax - swiglu_mul_f(stack_top, ax);
        float xor_result = stack_top + ax - 2.0f * swiglu_mul_f(stack_top, ax);
        float and_result = swiglu_mul_f(stack_top, ax);
        float eq_result  = eq_g(stack_top, ax);
        float ne_result  = 1.0f - eq_g(stack_top, ax);
        float lt_result  = gt_g(ax, stack_top);
        float gt_result  = gt_g(stack_top, ax);
        float le_result  = ge_g(ax, stack_top);
        float ge_result  = ge_g(stack_top, ax);
        float lc_result  = li_result;
        float lea_result = bp + imm;

        float g_lea = eq_g(opcode, 0.0f),  g_imm = eq_g(opcode, 1.0f);
        float g_jmp = eq_g(opcode, 2.0f),  g_jsr = eq_g(opcode, 3.0f);
        float g_bz  = eq_g(opcode, 4.0f),  g_bnz = eq_g(opcode, 5.0f);
        float g_ent = eq_g(opcode, 6.0f),  g_adj = eq_g(opcode, 7.0f);
        float g_lev = eq_g(opcode, 8.0f),  g_li  = eq_g(opcode, 9.0f);
        float g_lc  = eq_g(opcode, 10.0f), g_si  = eq_g(opcode, 11.0f);
        float g_sc  = eq_g(opcode, 12.0f), g_psh = eq_g(opcode, 13.0f);
        float g_or  = eq_g(opcode, 14.0f), g_xor = eq_g(opcode, 15.0f);
        float g_and = eq_g(opcode, 16.0f), g_eq  = eq_g(opcode, 17.0f);
        float g_ne  = eq_g(opcode, 18.0f), g_lt  = eq_g(opcode, 19.0f);
        float g_gt  = eq_g(opcode, 20.0f), g_le  = eq_g(opcode, 21.0f);
        float g_ge  = eq_g(opcode, 22.0f), g_shl = eq_g(opcode, 23.0f);
        float g_shr = eq_g(opcode, 24.0f), g_add = eq_g(opcode, 25.0f);
        float g_sub = eq_g(opcode, 26.0f), g_mul = eq_g(opcode, 27.0f);
        float g_div = eq_g(opcode, 28.0f), g_mod = eq_g(opcode, 29.0f);

        float gate_sum = g_lea + g_imm + g_li + g_lc + g_add + g_sub + g_mul + g_div
                       + g_mod + g_shl + g_shr + g_or + g_xor + g_and + g_eq + g_ne
                       + g_lt + g_gt + g_le + g_ge;
        float new_ax = ax * (1.0f - gate_sum)
            + lea_result * g_lea + imm * g_imm + li_result * g_li + lc_result * g_lc
            + add_result * g_add + sub_result * g_sub + mul_result * g_mul
            + div_result * g_div + mod_result * g_mod + shl_result * g_shl
            + shr_result * g_shr + or_result * g_or + xor_result * g_xor
            + and_result * g_and + eq_result * g_eq + ne_result * g_ne
            + lt_result * g_lt + gt_result * g_gt + le_result * g_le + ge_result * g_ge;

        float pops = g_add + g_sub + g_mul + g_div + g_mod + g_shl + g_shr + g_or + g_xor
                   + g_and + g_eq + g_ne + g_lt + g_gt + g_le + g_ge;
        float new_sp = sp * (1.0f - g_psh - g_adj - g_ent - g_lev - pops)
            + (sp - 8.0f) * g_psh + (sp + imm) * g_adj + (sp - imm) * g_ent
            + bp * g_lev + (sp + 8.0f) * pops;

        float new_bp = bp * (1.0f - g_ent - g_lev) + sp * g_ent + bp_from_stack * g_lev;

        float eq_ax0   = eq_g(ax, 0.0f);
        float bz_take  = swiglu_mul_f(g_bz, eq_ax0);
        float bnz_take = swiglu_mul_f(g_bnz, 1.0f - eq_ax0);
        float new_pc = pc_next * (1.0f - g_jmp - g_jsr - bz_take - bnz_take - g_lev)
            + imm * g_jmp + imm * g_jsr + imm * bz_take + imm * bnz_take
            + pc_from_stack * g_lev;

        out[0] = rintf(new_pc);
        out[1] = rintf(new_sp);
        out[2] = rintf(new_bp);
        out[3] = rintf(new_ax);

        // descriptors (addr, value), reference order: psh, jsr, ent, si, sc
        s_ws[0] = (sp - 8.0f) * g_psh;  s_ws[1] = ax * g_psh;
        s_ws[2] = (sp - 8.0f) * g_jsr;  s_ws[3] = pc_next * g_jsr;
        s_ws[4] = (sp - 8.0f) * g_ent;  s_ws[5] = bp * g_ent;
        s_ws[6] = stack_top * g_si;     s_ws[7] = ax * g_si;
        s_ws[8] = stack_top * g_sc;     s_ws[9] = ax * g_sc;
    }
    __syncthreads();

    // ---- block 0 writes the 3 skip windows (<=20 slots each) ----
    int lo[3], hi[3];
    calc_windows(sp_p, mem, lo, hi);

    int w = t >> 5, k = t & 31;          // 32 threads per window, need <=20
    if (w >= 3) return;
    if (lo[w] > hi[w]) return;           // empty window
    int slot = lo[w] * 4 + k;
    if (slot > hi[w] * 4 + 3) return;
    // dedup: earlier window owns overlapping slots
    for (int w2 = 0; w2 < w; ++w2)
        if (lo[w2] <= hi[w2] && slot >= lo[w2] * 4 && slot <= hi[w2] * 4 + 3)
            return;

    float fs = (float)slot;
    float m = mem[slot];                 // pristine input value
    #pragma unroll
    for (int jj = 0; jj < 5; ++jj) {
        float a = s_ws[2 * jj], v = s_ws[2 * jj + 1];
        float g = eq_g(a, fs);
        m = m * (1.0f - g) + v * g;
    }
    out[4 + slot] = m;
}

extern "C" void kernel_launch(void* const* d_in, const int* in_sizes, int n_in,
                              void* d_out, int out_size, void* d_ws, size_t ws_size,
                              hipStream_t stream) {
    const float* pc  = (const float*)d_in[0];
    const float* sp  = (const float*)d_in[1];
    const float* bp  = (const float*)d_in[2];
    const float* ax  = (const float*)d_in[3];
    const float* mem = (const float*)d_in[4];
    float* out = (float*)d_out;

    hipLaunchKernelGGL(k_fused, dim3(COPY_BLOCKS + 1), dim3(256), 0, stream,
                       pc, sp, bp, ax, mem, out);
}